// Round 12
// baseline (248.524 us; speedup 1.0000x reference)
//
#include <hip/hip_runtime.h>
#include <hip/hip_bf16.h>

#define TT 4096
#define NCH 32
#define BB 2

// Intermediates in static device globals. Every element read is written
// earlier in the same launch.
__device__ float g_tok[(size_t)BB*TT*128];
__device__ float g_Qp [(size_t)BB*TT*128];
__device__ float g_Kp [(size_t)BB*TT*128];
__device__ float g_Vg [(size_t)BB*TT*128];
__device__ float g_Pv [(size_t)BB*TT*128];
__device__ float g_Pg [(size_t)BB*TT*128];
__device__ float g_Ssum[(size_t)BB*NCH*16384];
__device__ float g_Spre[(size_t)BB*NCH*16384];
__device__ float g_Sk [(size_t)BB*NCH*128];
__device__ float g_Skp[(size_t)BB*NCH*128];

__device__ __forceinline__ float phi_f(float x){ return x > 0.f ? x + 1.f : __expf(x); }
__device__ __forceinline__ float sigm_f(float x){ return 1.f/(1.f+__expf(-x)); }

// Build tokens: [xs, ys] rows + [query_x, 0] final row.
__global__ __launch_bounds__(256) void k0_build(const float* __restrict__ xs,
                                                const float* __restrict__ ys,
                                                const float* __restrict__ qx){
  long e = (long)blockIdx.x * 256 + threadIdx.x;
  int col = (int)(e & 127);
  long r = e >> 7;
  int t = (int)(r & (TT-1));
  int b = (int)(r >> 12);
  float v;
  if (t < TT-1) {
    v = (col < 127) ? xs[((long)b*(TT-1) + t)*127 + col] : ys[(long)b*(TT-1) + t];
  } else {
    v = (col < 127) ? qx[(long)b*127 + col] : 0.f;
  }
  g_tok[e] = v;
}

// LN1 + projection GEMM, fused. 128 rows x 128 cols per block, k=128.
// grid = 64 tiles * 4 mats; mat 0=Q(phi) 1=K(phi) 2=V(raw->Pv) 3=G(raw->Pg).
__global__ __launch_bounds__(256) void k1b_gemm(
    const float* __restrict__ Wq, const float* __restrict__ Wk,
    const float* __restrict__ Wv, const float* __restrict__ Wg,
    const float* __restrict__ lnw, const float* __restrict__ lnb)
{
  __shared__ float xl[128*132];   // LN(x) row-major
  __shared__ float wt[128*132];   // W^T [k][j]
  int tid = threadIdx.x;
  int mat = blockIdx.x & 3;
  long row0 = (long)(blockIdx.x >> 2) * 128;
  const float* W = (mat==0) ? Wq : (mat==1) ? Wk : (mat==2) ? Wv : Wg;
  bool isQK = (mat < 2);
  for (int i=0;i<16;i++){
    int ts = (tid & 31) + 32*(i & 3);     // output col j
    int hc = (tid >> 5) + 8*(i >> 2);     // k group of 4
    int wr = isQK ? (ts < 127 ? ts : 126) : ts;
    float4 v = *(const float4*)(W + (long)wr*128 + hc*4);
    wt[(hc*4+0)*132+ts] = v.x;
    wt[(hc*4+1)*132+ts] = v.y;
    wt[(hc*4+2)*132+ts] = v.z;
    wt[(hc*4+3)*132+ts] = v.w;
  }
  {
    int row = tid >> 1, half = tid & 1;
    const float* src = g_tok + (row0 + row)*128 + half*64;
    float s1 = 0.f, s2 = 0.f;
    for (int u=0; u<16; u++){
      float4 v = *(const float4*)(src + u*4);
      s1 += v.x+v.y+v.z+v.w;
      s2 += v.x*v.x+v.y*v.y+v.z*v.z+v.w*v.w;
      *(float4*)&xl[row*132 + half*64 + u*4] = v;
    }
    s1 += __shfl_xor(s1, 1); s2 += __shfl_xor(s2, 1);
    float mean = s1*(1.f/128.f);
    float var  = s2*(1.f/128.f) - mean*mean;
    float rstd = rsqrtf(var + 1e-5f);
    for (int u=0; u<16; u++){
      int cc = half*64 + u*4;
      float4 v  = *(float4*)&xl[row*132 + cc];
      float4 w4 = *(const float4*)(lnw + cc);
      float4 b4 = *(const float4*)(lnb + cc);
      v.x = (v.x-mean)*rstd*w4.x + b4.x;
      v.y = (v.y-mean)*rstd*w4.y + b4.y;
      v.z = (v.z-mean)*rstd*w4.z + b4.z;
      v.w = (v.w-mean)*rstd*w4.w + b4.w;
      *(float4*)&xl[row*132 + cc] = v;
    }
  }
  __syncthreads();
  int g = tid >> 4, c = tid & 15;
  float acc[8][8];
  #pragma unroll
  for (int i=0;i<8;i++)
    #pragma unroll
    for (int j=0;j<8;j++) acc[i][j]=0.f;
  for (int k=0;k<128;k++){
    float xr[8];
    #pragma unroll
    for (int i=0;i<8;i++) xr[i] = xl[(g+16*i)*132 + k];
    float4 wa = *(const float4*)&wt[k*132 + c*4];
    float4 wb = *(const float4*)&wt[k*132 + 64 + c*4];
    float wc[8] = {wa.x,wa.y,wa.z,wa.w,wb.x,wb.y,wb.z,wb.w};
    #pragma unroll
    for (int i=0;i<8;i++)
      #pragma unroll
      for (int j=0;j<8;j++)
        acc[i][j] += xr[i]*wc[j];
  }
  if (isQK){
    float* dst = (mat==0) ? g_Qp : g_Kp;
    #pragma unroll
    for (int i=0;i<8;i++){
      long rr = row0 + g + 16*i;
      float v0[4], v1[4];
      #pragma unroll
      for (int j=0;j<4;j++) v0[j] = phi_f(acc[i][j]);
      #pragma unroll
      for (int j=0;j<4;j++){
        int col = 64 + c*4 + j;
        v1[j] = (col < 127) ? phi_f(acc[i][4+j]) : 0.f;
      }
      *(float4*)(dst + rr*128 + c*4)      = make_float4(v0[0],v0[1],v0[2],v0[3]);
      *(float4*)(dst + rr*128 + 64 + c*4) = make_float4(v1[0],v1[1],v1[2],v1[3]);
    }
  } else {
    float* dst = (mat==2) ? g_Pv : g_Pg;
    #pragma unroll
    for (int i=0;i<8;i++){
      long rr = row0 + g + 16*i;
      *(float4*)(dst + rr*128 + c*4)      = make_float4(acc[i][0],acc[i][1],acc[i][2],acc[i][3]);
      *(float4*)(dst + rr*128 + 64 + c*4) = make_float4(acc[i][4],acc[i][5],acc[i][6],acc[i][7]);
    }
  }
}

// Vg = Pv * sigmoid(Pg + b), vectorized.
__global__ __launch_bounds__(256) void k1c_vg(const float* __restrict__ Wgb){
  long e = ((long)blockIdx.x*256 + threadIdx.x) * 4;
  int j = (int)(e & 127);
  float4 pv = *(const float4*)(g_Pv + e);
  float4 pg = *(const float4*)(g_Pg + e);
  float4 gb = *(const float4*)(Wgb + j);
  float4 o;
  o.x = pv.x * sigm_f(pg.x + gb.x);
  o.y = pv.y * sigm_f(pg.y + gb.y);
  o.z = pv.z * sigm_f(pg.z + gb.z);
  o.w = pv.w * sigm_f(pg.w + gb.w);
  *(float4*)(g_Vg + e) = o;
}

// Per-chunk state sums: Ssum[b][c][h][m] = sum_t Kp*Vg ; Sk[b][c][h] = sum_t Kp.
__global__ __launch_bounds__(256) void k2_chunksum()
{
  __shared__ float vgs[16][128];
  __shared__ float kps[16][32];
  int tid = threadIdx.x;
  int ht = blockIdx.x & 3;
  int c  = (blockIdx.x >> 2) & 31;
  int b  = blockIdx.x >> 7;
  int hl = tid >> 3, mg = tid & 7, m0 = mg << 4;
  int h  = ht*32 + hl;
  float acc[16];
  #pragma unroll
  for (int i=0;i<16;i++) acc[i]=0.f;
  float sk = 0.f;
  long base = ((long)b*TT + c*128)*128;
  for (int tb=0; tb<8; tb++){
    __syncthreads();
    { int e = tid*8; int ts = e >> 7; int cc = e & 127;
      const float* s = g_Vg + base + (long)(tb*16+ts)*128 + cc;
      *(float4*)&vgs[ts][cc]   = *(const float4*)s;
      *(float4*)&vgs[ts][cc+4] = *(const float4*)(s+4); }
    { int e = tid*2; int ts = e >> 5; int hh = e & 31;
      const float* s = g_Kp + base + (long)(tb*16+ts)*128 + ht*32 + hh;
      kps[ts][hh] = s[0]; kps[ts][hh+1] = s[1]; }
    __syncthreads();
    for (int ts=0; ts<16; ts++){
      float kp = kps[ts][hl];
      sk += kp;
      #pragma unroll
      for (int i=0;i<16;i++) acc[i] += kp * vgs[ts][m0+i];
    }
  }
  long so = (((long)b*NCH + c)*128 + h)*128 + m0;
  #pragma unroll
  for (int i=0;i<16;i+=4)
    *(float4*)(g_Ssum + so + i) = make_float4(acc[i],acc[i+1],acc[i+2],acc[i+3]);
  if (mg==0) g_Sk[((long)b*NCH + c)*128 + h] = sk;
}

// Exclusive prefix scan over chunks, ILP version: preload all 32 chunk values
// as independent loads (one latency exposure), then register prefix + stores.
// Blocks 0..31: Spre (one float4 column per thread). Block 32: Sk.
__global__ __launch_bounds__(256) void k3_scan()
{
  if (blockIdx.x < 32){
    int gid = blockIdx.x*256 + threadIdx.x;   // 8192 threads = BB*4096 float4 cols
    int b  = gid >> 12;
    int e4 = gid & 4095;
    long base = ((long)b*NCH)*16384 + (long)e4*4;
    float4 v[NCH];
    #pragma unroll
    for (int c=0;c<NCH;c++)
      v[c] = *(const float4*)(g_Ssum + base + (long)c*16384);
    float4 run = make_float4(0.f,0.f,0.f,0.f);
    #pragma unroll
    for (int c=0;c<NCH;c++){
      *(float4*)(g_Spre + base + (long)c*16384) = run;
      run.x += v[c].x; run.y += v[c].y; run.z += v[c].z; run.w += v[c].w;
    }
  } else {
    int b = threadIdx.x >> 7, h = threadIdx.x & 127;
    long base = ((long)b*NCH)*128 + h;
    float v[NCH];
    #pragma unroll
    for (int c=0;c<NCH;c++) v[c] = g_Sk[base + c*128];
    float run = 0.f;
    #pragma unroll
    for (int c=0;c<NCH;c++){
      g_Skp[base + c*128] = run;
      run += v[c];
    }
  }
}

// Fused inter+intra attention + Wo + residual + LN2, in place on g_tok.
// Grid: BB*NCH*4 = 256 blocks; block owns 32 rows of one chunk.
// Thread tiling: rg=tid>>5 (rows 4rg..4rg+3), cs=tid&31 (cols cs*4..cs*4+3).
// bufb stride 133 (odd) so 8-address row-broadcast reads spread across banks.
__global__ __launch_bounds__(256) void k4_fused(
    const float* __restrict__ Wo,
    const float* __restrict__ ln2w, const float* __restrict__ ln2b)
{
  __shared__ float spl[128*132];   // Spre padded [h*132+n]           (67.6 KB)
  __shared__ float ktl[128*132];   // K^T [h][ts] -> Vg flat -> Wo^T  (67.6 KB)
  __shared__ float bufb[32*133];   // Qp rows -> A rows (str 133)     (17.0 KB)
  __shared__ float skl[128];
  int tid = threadIdx.x;
  int rq = blockIdx.x & 3;
  int c  = (blockIdx.x >> 2) & 31;
  int b  = blockIdx.x >> 7;
  int r0 = rq*32;
  long cbase = ((long)b*TT + c*128)*128;
  long sbase = ((long)b*NCH + c)*16384;

  for (int i=0;i<16;i++){
    int e = i*1024 + tid*4;
    int h = e >> 7, n = e & 127;
    *(float4*)&spl[h*132+n] = *(const float4*)(g_Spre + sbase + e);
  }
  if (tid < 128) skl[tid] = g_Skp[((long)b*NCH + c)*128 + tid];
  for (int i=0;i<4;i++){
    int e = i*1024 + tid*4;
    int row = e >> 7, cc = e & 127;
    *(float4*)&bufb[row*133+cc] = *(const float4*)(g_Qp + cbase + (long)(r0+row)*128 + cc);
  }
  for (int i=0;i<16;i++){
    int ts = (tid & 31) + 32*(i & 3);
    int hc = (tid >> 5) + 8*(i >> 2);
    float4 v = *(const float4*)(g_Kp + cbase + (long)ts*128 + hc*4);
    ktl[(hc*4+0)*132 + ts] = v.x;
    ktl[(hc*4+1)*132 + ts] = v.y;
    ktl[(hc*4+2)*132 + ts] = v.z;
    ktl[(hc*4+3)*132 + ts] = v.w;
  }
  __syncthreads();

  int rg = tid >> 5, cs = tid & 31;
  int n0 = cs*4;
  float acc2[4][4], a[4][4];
  #pragma unroll
  for (int r=0;r<4;r++)
    #pragma unroll
    for (int j=0;j<4;j++){ acc2[r][j]=0.f; a[r][j]=0.f; }
  float den[4] = {0.f,0.f,0.f,0.f};
  for (int h=0;h<128;h++){
    float sv = skl[h];
    float4 s4 = *(const float4*)&spl[h*132 + n0];
    float4 k4 = *(const float4*)&ktl[h*132 + n0];
    #pragma unroll
    for (int r=0;r<4;r++){
      float qv = bufb[(4*rg+r)*133 + h];
      den[r] += qv*sv;
      acc2[r][0]+=qv*s4.x; acc2[r][1]+=qv*s4.y; acc2[r][2]+=qv*s4.z; acc2[r][3]+=qv*s4.w;
      a[r][0]+=qv*k4.x; a[r][1]+=qv*k4.y; a[r][2]+=qv*k4.z; a[r][3]+=qv*k4.w;
    }
  }
  // causal mask (inclusive, chunk-local) + intra denominator
  float inv[4];
  #pragma unroll
  for (int r=0;r<4;r++){
    int tq = r0 + 4*rg + r;
    float dena = 0.f;
    #pragma unroll
    for (int j=0;j<4;j++){
      if (n0 + j > tq) a[r][j] = 0.f;
      dena += a[r][j];
    }
    dena += __shfl_xor(dena, 1);
    dena += __shfl_xor(dena, 2);
    dena += __shfl_xor(dena, 4);
    dena += __shfl_xor(dena, 8);
    dena += __shfl_xor(dena, 16);
    inv[r] = 1.f / fmaxf(den[r] + dena, 1e-6f);
  }
  __syncthreads();
  // A -> bufb ; Vg -> ktl flat [ts*128+n]
  #pragma unroll
  for (int r=0;r<4;r++)
    *(float4*)&bufb[(4*rg+r)*133 + n0] = make_float4(a[r][0],a[r][1],a[r][2],a[r][3]);
  for (int i=0;i<16;i++){
    int e = i*1024 + tid*4;
    *(float4*)&ktl[e] = *(const float4*)(g_Vg + cbase + e);
  }
  __syncthreads();
  for (int ts=0; ts<128; ts++){
    float4 v4 = *(const float4*)&ktl[ts*128 + n0];
    #pragma unroll
    for (int r=0;r<4;r++){
      float av = bufb[(4*rg+r)*133 + ts];
      acc2[r][0]+=av*v4.x; acc2[r][1]+=av*v4.y; acc2[r][2]+=av*v4.z; acc2[r][3]+=av*v4.w;
    }
  }
  __syncthreads();
  // attn -> bufb ; Wo^T -> ktl [m][n] padded (lane-diagonal)
  #pragma unroll
  for (int r=0;r<4;r++)
    *(float4*)&bufb[(4*rg+r)*133 + n0] =
      make_float4(acc2[r][0]*inv[r],acc2[r][1]*inv[r],acc2[r][2]*inv[r],acc2[r][3]*inv[r]);
  for (int i=0;i<16;i++){
    int n  = (tid & 31) + 32*(i & 3);
    int mc = (tid >> 5) + 8*(i >> 2);
    float4 v = *(const float4*)(Wo + (long)n*128 + mc*4);
    ktl[(mc*4+0)*132 + n] = v.x;
    ktl[(mc*4+1)*132 + n] = v.y;
    ktl[(mc*4+2)*132 + n] = v.z;
    ktl[(mc*4+3)*132 + n] = v.w;
  }
  __syncthreads();
  float s[4][4];
  #pragma unroll
  for (int r=0;r<4;r++)
    #pragma unroll
    for (int j=0;j<4;j++) s[r][j]=0.f;
  for (int m=0;m<128;m++){
    float4 w4 = *(const float4*)&ktl[m*132 + n0];
    #pragma unroll
    for (int r=0;r<4;r++){
      float av = bufb[(4*rg+r)*133 + m];
      s[r][0]+=av*w4.x; s[r][1]+=av*w4.y; s[r][2]+=av*w4.z; s[r][3]+=av*w4.w;
    }
  }
  float4 lw = *(const float4*)(ln2w+n0);
  float4 lb = *(const float4*)(ln2b+n0);
  #pragma unroll
  for (int r=0;r<4;r++){
    long trow = (long)b*TT + c*128 + r0 + 4*rg + r;
    float4 t4 = *(const float4*)(g_tok + trow*128 + n0);
    float o0 = t4.x + 0.1f*s[r][0];
    float o1 = t4.y + 0.1f*s[r][1];
    float o2 = t4.z + 0.1f*s[r][2];
    float o3 = t4.w + 0.1f*s[r][3];
    float s1 = o0+o1+o2+o3;
    float s2 = o0*o0+o1*o1+o2*o2+o3*o3;
    s1 += __shfl_xor(s1,1);  s2 += __shfl_xor(s2,1);
    s1 += __shfl_xor(s1,2);  s2 += __shfl_xor(s2,2);
    s1 += __shfl_xor(s1,4);  s2 += __shfl_xor(s2,4);
    s1 += __shfl_xor(s1,8);  s2 += __shfl_xor(s2,8);
    s1 += __shfl_xor(s1,16); s2 += __shfl_xor(s2,16);
    float mean = s1*(1.f/128.f);
    float var  = s2*(1.f/128.f) - mean*mean;
    float rstd = rsqrtf(var + 1e-5f);
    float4 o;
    o.x = (o0-mean)*rstd*lw.x + lb.x;
    o.y = (o1-mean)*rstd*lw.y + lb.y;
    o.z = (o2-mean)*rstd*lw.z + lb.z;
    o.w = (o3-mean)*rstd*lw.w + lb.w;
    *(float4*)(g_tok + trow*128 + n0) = o;
  }
}

__global__ __launch_bounds__(128) void k5_pred(const float* __restrict__ pw,
                                               float* __restrict__ out){
  __shared__ float red[2];
  int b = blockIdx.x, tid = threadIdx.x;
  float v = g_tok[((long)b*TT + TT-1)*128 + tid] * pw[tid];
  #pragma unroll
  for (int off=1; off<64; off<<=1) v += __shfl_xor(v, off);
  if ((tid & 63) == 0) red[tid>>6] = v;
  __syncthreads();
  if (tid==0) out[b] = red[0] + red[1];
}

extern "C" void kernel_launch(void* const* d_in, const int* in_sizes, int n_in,
                              void* d_out, int out_size, void* d_ws, size_t ws_size,
                              hipStream_t stream)
{
  (void)in_sizes; (void)n_in; (void)out_size; (void)d_ws; (void)ws_size;
  const float* xs   = (const float*)d_in[0];
  const float* ys   = (const float*)d_in[1];
  const float* qx   = (const float*)d_in[2];
  const float* Wq   = (const float*)d_in[3];
  const float* Wk   = (const float*)d_in[4];
  const float* Wv   = (const float*)d_in[5];
  const float* Wgw  = (const float*)d_in[6];
  const float* Wgb  = (const float*)d_in[7];
  const float* Wo   = (const float*)d_in[8];
  const float* ln1w = (const float*)d_in[9];
  const float* ln1b = (const float*)d_in[10];
  const float* ln2w = (const float*)d_in[11];
  const float* ln2b = (const float*)d_in[12];
  const float* predw= (const float*)d_in[13];

  k0_build<<<4096, 256, 0, stream>>>(xs, ys, qx);

  for (int l=0; l<2; l++){
    const float* Wq_l  = Wq  + (size_t)l*127*128;
    const float* Wk_l  = Wk  + (size_t)l*127*128;
    const float* Wv_l  = Wv  + (size_t)l*128*128;
    const float* Wgw_l = Wgw + (size_t)l*128*128;
    const float* Wgb_l = Wgb + (size_t)l*128;
    const float* Wo_l  = Wo  + (size_t)l*128*128;
    const float* l1w = ln1w + (size_t)l*128;
    const float* l1b = ln1b + (size_t)l*128;
    const float* l2w = ln2w + (size_t)l*128;
    const float* l2b = ln2b + (size_t)l*128;

    k1b_gemm<<<256, 256, 0, stream>>>(Wq_l, Wk_l, Wv_l, Wgw_l, l1w, l1b);
    k1c_vg<<<1024, 256, 0, stream>>>(Wgb_l);
    k2_chunksum<<<256, 256, 0, stream>>>();
    k3_scan<<<33, 256, 0, stream>>>();
    k4_fused<<<256, 256, 0, stream>>>(Wo_l, l2w, l2b);
  }
  k5_pred<<<BB, 128, 0, stream>>>(predw, (float*)d_out);
}